// Round 3
// baseline (596.405 us; speedup 1.0000x reference)
//
#include <hip/hip_runtime.h>

typedef _Float16 f16;
typedef _Float16 f16x8 __attribute__((ext_vector_type(8)));
typedef float    f32x4 __attribute__((ext_vector_type(4)));

#define B_ 4
#define C_ 512
#define N_ 4096
#define M_ 64

// ---------------------------------------------------------------------------
// Kernel T: x [B][C][N] fp32  ->  x_t [B][N][C] f16   (LDS tile transpose)
// ---------------------------------------------------------------------------
__global__ __launch_bounds__(256) void transpose_cast(
    const float* __restrict__ x, f16* __restrict__ xt)
{
    __shared__ float sT[64][65];
    const int n0 = blockIdx.x * 64;
    const int c0 = blockIdx.y * 64;
    const int b  = blockIdx.z;
    const int tid = threadIdx.x;

    #pragma unroll
    for (int i = 0; i < 16; ++i) {
        int e = i * 256 + tid;
        int c = e >> 6, n = e & 63;
        sT[n][c] = x[((size_t)(b * C_ + c0 + c)) * N_ + (n0 + n)];
    }
    __syncthreads();
    #pragma unroll
    for (int i = 0; i < 16; ++i) {
        int e = i * 256 + tid;
        int n = e >> 6, c = e & 63;
        xt[((size_t)(b * N_ + n0 + n)) * C_ + (c0 + c)] = (f16)sT[n][c];
    }
}

// ---------------------------------------------------------------------------
// Kernel A: fused qkv GEMM via mfma_f32_16x16x32_f16. (unchanged, validated)
// ---------------------------------------------------------------------------
__global__ __launch_bounds__(512) void qkv_gemm(
    const f16* __restrict__ xt,
    const float* __restrict__ Wq, const float* __restrict__ bq,
    const float* __restrict__ Wk, const float* __restrict__ bk,
    const float* __restrict__ Wv, const float* __restrict__ bv,
    f16* __restrict__ qt, f16* __restrict__ kt, f16* __restrict__ vh)
{
    const int tid  = threadIdx.x;
    const int w    = tid >> 6;
    const int lane = tid & 63;
    const int l15  = lane & 15;
    const int quad = lane >> 4;
    const int nBase = blockIdx.x * 128;
    const int oseg  = blockIdx.y;
    const int b     = blockIdx.z;
    const int ot16  = w & 3;
    const int nhalf = w >> 2;

    const float* Wsel;
    if (oseg == 0)      Wsel = Wq;
    else if (oseg == 1) Wsel = Wk;
    else                Wsel = Wv + (size_t)(oseg - 2) * 64 * C_;

    const int orow = ot16 * 16 + l15;
    const float* wptr = Wsel + (size_t)orow * C_;

    f32x4 acc[4] = {};

    for (int c0 = 0; c0 < C_; c0 += 32) {
        f16x8 a8;
        {
            const float4 w0 = *(const float4*)(wptr + c0 + quad * 8);
            const float4 w1 = *(const float4*)(wptr + c0 + quad * 8 + 4);
            a8[0]=(f16)w0.x; a8[1]=(f16)w0.y; a8[2]=(f16)w0.z; a8[3]=(f16)w0.w;
            a8[4]=(f16)w1.x; a8[5]=(f16)w1.y; a8[6]=(f16)w1.z; a8[7]=(f16)w1.w;
        }
        #pragma unroll
        for (int ns = 0; ns < 4; ++ns) {
            int n = nBase + nhalf * 64 + ns * 16 + l15;
            f16x8 b8 = *(const f16x8*)(xt + ((size_t)(b * N_ + n)) * C_ + c0 + quad * 8);
            acc[ns] = __builtin_amdgcn_mfma_f32_16x16x32_f16(a8, b8, acc[ns], 0, 0, 0);
        }
    }

    #pragma unroll
    for (int ns = 0; ns < 4; ++ns) {
        int n = nBase + nhalf * 64 + ns * 16 + l15;
        #pragma unroll
        for (int r = 0; r < 4; ++r) {
            int olocal = ot16 * 16 + quad * 4 + r;
            float bias;
            if (oseg == 0)      bias = bq[olocal];
            else if (oseg == 1) bias = bk[olocal];
            else                bias = bv[(oseg - 2) * 64 + olocal];
            f16 h = (f16)(acc[ns][r] + bias);
            if (oseg == 0) {
                qt[((size_t)(b * N_ + n)) * M_ + olocal] = h;
            } else if (oseg == 1) {
                kt[((size_t)(b * N_ + n)) * M_ + olocal] = h;
            } else {
                int c = (oseg - 2) * 64 + olocal;
                vh[((size_t)(b * C_ + c)) * N_ + n] = h;
            }
        }
    }
}

// ---------------------------------------------------------------------------
// Kernel B: two-pass attention, fused in one kernel. TI=64, 1024 thr (16 waves).
// Pass 1: rowmax m_i via lane-local register max (no LDS/barriers in loop).
// Pass 2: p' = exp(s - m_i) -> f16 LDS (double-buffered, 1 barrier/tile),
//         PV MFMA with lane-local l accumulation; epilogue /l, *gamma, +x.
// Score mapping (16 waves): iq = w&3 (i 16-slice), jq = w>>2 (j 16-slice).
// PV mapping: c0w = (w&7)*64 (channel slice), ph = w>>3 (i 32-half).
// ---------------------------------------------------------------------------
#define SP 72   // f16 row stride: 144B, 16B-aligned

__global__ __launch_bounds__(1024) void attn(
    const f16* __restrict__ qt, const f16* __restrict__ kt,
    const f16* __restrict__ vh, const float* __restrict__ x,
    const float* __restrict__ gamma, float* __restrict__ out)
{
    __shared__ __align__(16) f16   sP[2][64][SP];   // 18.4 KB
    __shared__ __align__(16) float sRm[4][64];      // rowmax partials per jq
    __shared__ __align__(16) float sRl[4][64];      // l partials per jq

    const int tid  = threadIdx.x;
    const int w    = tid >> 6;                      // 0..15
    const int lane = tid & 63;
    const int l15  = lane & 15;
    const int quad = lane >> 4;

    // XCD-swizzled block -> (b, i0): batch pinned to an XCD pair for v L2 reuse
    const int lin  = blockIdx.x;                    // 0..255
    const int b    = (lin & 7) >> 1;
    const int iblk = ((lin >> 3) << 1) | (lin & 1); // 0..63
    const int i0   = iblk * 64;

    const int iq = w & 3;                           // score i 16-slice
    const int jq = w >> 2;                          // score j 16-slice
    const int c0w = (w & 7) * 64;                   // PV channel slice
    const int ph  = w >> 3;                         // PV i 32-half

    // q A-fragments for this wave's score rows (block-invariant)
    f16x8 aq[2];
    #pragma unroll
    for (int kh = 0; kh < 2; ++kh)
        aq[kh] = *(const f16x8*)(qt + ((size_t)(b * N_ + i0 + iq * 16 + l15)) * M_
                                 + kh * 32 + quad * 8);
    const size_t kbase = (size_t)b * N_ * M_;

    // ---------------- pass 1: rowmax (registers only) ----------------
    f32x4 mx = { -3.0e38f, -3.0e38f, -3.0e38f, -3.0e38f };
    for (int j0 = 0; j0 < N_; j0 += 64) {
        f32x4 s = {};
        #pragma unroll
        for (int kh = 0; kh < 2; ++kh) {
            f16x8 bk8 = *(const f16x8*)(kt + kbase + ((size_t)(j0 + jq * 16 + l15)) * M_
                                        + kh * 32 + quad * 8);
            s = __builtin_amdgcn_mfma_f32_16x16x32_f16(aq[kh], bk8, s, 0, 0, 0);
        }
        #pragma unroll
        for (int r = 0; r < 4; ++r) mx[r] = fmaxf(mx[r], s[r]);
    }
    // reduce over l15 lanes (columns) -> row max for this jq quarter
    #pragma unroll
    for (int r = 0; r < 4; ++r) {
        #pragma unroll
        for (int msk = 1; msk < 16; msk <<= 1)
            mx[r] = fmaxf(mx[r], __shfl_xor(mx[r], msk, 64));
    }
    if (l15 == 0) {
        #pragma unroll
        for (int r = 0; r < 4; ++r)
            sRm[jq][iq * 16 + quad * 4 + r] = mx[r];
    }
    __syncthreads();
    // each lane picks up final m for its 4 score rows
    float mrow[4];
    #pragma unroll
    for (int r = 0; r < 4; ++r) {
        int row = iq * 16 + quad * 4 + r;
        mrow[r] = fmaxf(fmaxf(sRm[0][row], sRm[1][row]),
                        fmaxf(sRm[2][row], sRm[3][row]));
    }
    __syncthreads();   // sRm reads done before... (cheap; keeps sP phase clean)

    // ---------------- pass 2: P + PV ----------------
    f32x4 acc[2][4] = {};          // [it(=i 16-sub of ph half)][ct]
    float l_acc[4] = {};           // lane-local l partial (score rows)
    int buf = 0;

    for (int j0 = 0; j0 < N_; j0 += 64) {
        // scores for (iq, jq) tile
        f32x4 s = {};
        #pragma unroll
        for (int kh = 0; kh < 2; ++kh) {
            f16x8 bk8 = *(const f16x8*)(kt + kbase + ((size_t)(j0 + jq * 16 + l15)) * M_
                                        + kh * 32 + quad * 8);
            s = __builtin_amdgcn_mfma_f32_16x16x32_f16(aq[kh], bk8, s, 0, 0, 0);
        }
        #pragma unroll
        for (int r = 0; r < 4; ++r) {
            float p = __expf(s[r] - mrow[r]);
            l_acc[r] += p;
            sP[buf][iq * 16 + quad * 4 + r][jq * 16 + l15] = (f16)p;
        }
        __syncthreads();           // the ONLY barrier per tile

        // PV: acc[it][ct] += P(it rows) x v(ct channels)
        f16x8 pa[2][2];
        #pragma unroll
        for (int it = 0; it < 2; ++it)
            #pragma unroll
            for (int kh = 0; kh < 2; ++kh)
                pa[it][kh] = *(const f16x8*)&sP[buf][(ph * 2 + it) * 16 + l15][kh * 32 + quad * 8];
        #pragma unroll
        for (int ct = 0; ct < 4; ++ct) {
            const int c = c0w + ct * 16 + l15;
            #pragma unroll
            for (int kh = 0; kh < 2; ++kh) {
                f16x8 vb = *(const f16x8*)(vh + ((size_t)(b * C_ + c)) * N_
                                           + j0 + kh * 32 + quad * 8);
                acc[0][ct] = __builtin_amdgcn_mfma_f32_16x16x32_f16(pa[0][kh], vb, acc[0][ct], 0, 0, 0);
                acc[1][ct] = __builtin_amdgcn_mfma_f32_16x16x32_f16(pa[1][kh], vb, acc[1][ct], 0, 0, 0);
            }
        }
        buf ^= 1;                  // next tile writes the other buffer (no 2nd barrier)
    }

    // ---------------- l reduction ----------------
    #pragma unroll
    for (int r = 0; r < 4; ++r) {
        #pragma unroll
        for (int msk = 1; msk < 16; msk <<= 1)
            l_acc[r] += __shfl_xor(l_acc[r], msk, 64);
    }
    if (l15 == 0) {
        #pragma unroll
        for (int r = 0; r < 4; ++r)
            sRl[jq][iq * 16 + quad * 4 + r] = l_acc[r];
    }
    __syncthreads();

    // ---------------- epilogue: out = gamma * feat / l + x ----------------
    const float g = gamma[0];
    #pragma unroll
    for (int it = 0; it < 2; ++it) {
        float linv[4];
        #pragma unroll
        for (int r = 0; r < 4; ++r) {
            int row = (ph * 2 + it) * 16 + quad * 4 + r;
            linv[r] = 1.0f / (sRl[0][row] + sRl[1][row] + sRl[2][row] + sRl[3][row]);
        }
        #pragma unroll
        for (int ct = 0; ct < 4; ++ct) {
            const int c = c0w + ct * 16 + l15;
            #pragma unroll
            for (int r = 0; r < 4; ++r) {
                int i = i0 + (ph * 2 + it) * 16 + quad * 4 + r;
                size_t idx = ((size_t)(b * C_ + c)) * N_ + i;
                out[idx] = g * (acc[it][ct][r] * linv[r]) + x[idx];
            }
        }
    }
}

// ---------------------------------------------------------------------------
extern "C" void kernel_launch(void* const* d_in, const int* in_sizes, int n_in,
                              void* d_out, int out_size, void* d_ws, size_t ws_size,
                              hipStream_t stream)
{
    const float* x     = (const float*)d_in[0];
    const float* Wq    = (const float*)d_in[1];
    const float* bq    = (const float*)d_in[2];
    const float* Wk    = (const float*)d_in[3];
    const float* bk    = (const float*)d_in[4];
    const float* Wv    = (const float*)d_in[5];
    const float* bv    = (const float*)d_in[6];
    const float* gamma = (const float*)d_in[7];
    float* out = (float*)d_out;

    char* ws = (char*)d_ws;
    f16* xt = (f16*)ws;                                   // B*N*C   (16 MB)
    f16* qt = (f16*)(ws + (size_t)B_ * N_ * C_ * 2);      // B*N*M   ( 2 MB)
    f16* kt = qt + (size_t)B_ * N_ * M_;                  // B*N*M   ( 2 MB)
    f16* vh = kt + (size_t)B_ * N_ * M_;                  // B*C*N   (16 MB)

    transpose_cast<<<dim3(N_ / 64, C_ / 64, B_), 256, 0, stream>>>(x, xt);
    qkv_gemm<<<dim3(N_ / 128, 10, B_), 512, 0, stream>>>(
        xt, Wq, bq, Wk, bk, Wv, bv, qt, kt, vh);
    attn<<<dim3(256), 1024, 0, stream>>>(qt, kt, vh, x, gamma, out);
}

// Round 4
// 468.952 us; speedup vs baseline: 1.2718x; 1.2718x over previous
//
#include <hip/hip_runtime.h>

typedef _Float16 f16;
typedef _Float16 f16x4 __attribute__((ext_vector_type(4)));
typedef _Float16 f16x8 __attribute__((ext_vector_type(8)));
typedef float    f32x4 __attribute__((ext_vector_type(4)));

#define B_ 4
#define C_ 512
#define N_ 4096
#define M_ 64

// Barrier that waits only on LDS ops (lgkmcnt), NOT vmcnt: lets prefetched
// global loads stay in flight across the barrier (AITER-style pipelining).
// sP is double-buffered; each wave's own ds_reads of buf are drained by its
// own lgkmcnt(0) one barrier before buf is rewritten -> race-free.
__device__ __forceinline__ void barrier_lgkm() {
    asm volatile("s_waitcnt lgkmcnt(0)\n\ts_barrier" ::: "memory");
}

// ---------------------------------------------------------------------------
// Kernel T: x [B][C][N] fp32  ->  x_t [B][N][C] f16   (LDS tile transpose)
// ---------------------------------------------------------------------------
__global__ __launch_bounds__(256) void transpose_cast(
    const float* __restrict__ x, f16* __restrict__ xt)
{
    __shared__ float sT[64][65];
    const int n0 = blockIdx.x * 64;
    const int c0 = blockIdx.y * 64;
    const int b  = blockIdx.z;
    const int tid = threadIdx.x;

    #pragma unroll
    for (int i = 0; i < 16; ++i) {
        int e = i * 256 + tid;
        int c = e >> 6, n = e & 63;
        sT[n][c] = x[((size_t)(b * C_ + c0 + c)) * N_ + (n0 + n)];
    }
    __syncthreads();
    #pragma unroll
    for (int i = 0; i < 16; ++i) {
        int e = i * 256 + tid;
        int n = e >> 6, c = e & 63;
        xt[((size_t)(b * N_ + n0 + n)) * C_ + (c0 + c)] = (f16)sT[n][c];
    }
}

// ---------------------------------------------------------------------------
// Kernel A: fused qkv GEMM via mfma_f32_16x16x32_f16. (validated rounds 2-3)
// ---------------------------------------------------------------------------
__global__ __launch_bounds__(512) void qkv_gemm(
    const f16* __restrict__ xt,
    const float* __restrict__ Wq, const float* __restrict__ bq,
    const float* __restrict__ Wk, const float* __restrict__ bk,
    const float* __restrict__ Wv, const float* __restrict__ bv,
    f16* __restrict__ qt, f16* __restrict__ kt, f16* __restrict__ vh)
{
    const int tid  = threadIdx.x;
    const int w    = tid >> 6;
    const int lane = tid & 63;
    const int l15  = lane & 15;
    const int quad = lane >> 4;
    const int nBase = blockIdx.x * 128;
    const int oseg  = blockIdx.y;
    const int b     = blockIdx.z;
    const int ot16  = w & 3;
    const int nhalf = w >> 2;

    const float* Wsel;
    if (oseg == 0)      Wsel = Wq;
    else if (oseg == 1) Wsel = Wk;
    else                Wsel = Wv + (size_t)(oseg - 2) * 64 * C_;

    const int orow = ot16 * 16 + l15;
    const float* wptr = Wsel + (size_t)orow * C_;

    f32x4 acc[4] = {};

    for (int c0 = 0; c0 < C_; c0 += 32) {
        f16x8 a8;
        {
            const float4 w0 = *(const float4*)(wptr + c0 + quad * 8);
            const float4 w1 = *(const float4*)(wptr + c0 + quad * 8 + 4);
            a8[0]=(f16)w0.x; a8[1]=(f16)w0.y; a8[2]=(f16)w0.z; a8[3]=(f16)w0.w;
            a8[4]=(f16)w1.x; a8[5]=(f16)w1.y; a8[6]=(f16)w1.z; a8[7]=(f16)w1.w;
        }
        #pragma unroll
        for (int ns = 0; ns < 4; ++ns) {
            int n = nBase + nhalf * 64 + ns * 16 + l15;
            f16x8 b8 = *(const f16x8*)(xt + ((size_t)(b * N_ + n)) * C_ + c0 + quad * 8);
            acc[ns] = __builtin_amdgcn_mfma_f32_16x16x32_f16(a8, b8, acc[ns], 0, 0, 0);
        }
    }

    #pragma unroll
    for (int ns = 0; ns < 4; ++ns) {
        int n = nBase + nhalf * 64 + ns * 16 + l15;
        #pragma unroll
        for (int r = 0; r < 4; ++r) {
            int olocal = ot16 * 16 + quad * 4 + r;
            float bias;
            if (oseg == 0)      bias = bq[olocal];
            else if (oseg == 1) bias = bk[olocal];
            else                bias = bv[(oseg - 2) * 64 + olocal];
            f16 h = (f16)(acc[ns][r] + bias);
            if (oseg == 0) {
                qt[((size_t)(b * N_ + n)) * M_ + olocal] = h;
            } else if (oseg == 1) {
                kt[((size_t)(b * N_ + n)) * M_ + olocal] = h;
            } else {
                int c = (oseg - 2) * 64 + olocal;
                vh[((size_t)(b * C_ + c)) * N_ + n] = h;
            }
        }
    }
}

// ---------------------------------------------------------------------------
// Kernel B: two-pass attention, operand-swapped MFMA.
//   Scores: S^T tile = mfma(A=k, B=q): C has col=i (lanes), row=j (regs)
//           -> vectorized ds_write_b64 of P into sP[i][j] f16.
//   PV:     feat^T = mfma(A=v, B=p): C has col=i (lanes), row=c (regs)
//           -> epilogue stores 64B-contiguous in i.
// 1024 thr = 16 waves. Scores: wave=(iq=w&3, jq=w>>2). PV: wave owns 32
// channels (c0w=w*32), all 64 i rows. v loads issued early + lgkm-only
// barrier keep them in flight across the barrier.
// ---------------------------------------------------------------------------
#define SP 72   // f16 row stride: 144B, 16B-aligned, 4-bank rotation per row

__global__ __launch_bounds__(1024) void attn(
    const f16* __restrict__ qt, const f16* __restrict__ kt,
    const f16* __restrict__ vh, const float* __restrict__ x,
    const float* __restrict__ gamma, float* __restrict__ out)
{
    __shared__ __align__(16) f16   sP[2][64][SP];   // 18.4 KB
    __shared__ __align__(16) float sRm[4][64];
    __shared__ __align__(16) float sRl[4][64];

    const int tid  = threadIdx.x;
    const int w    = tid >> 6;                      // 0..15
    const int lane = tid & 63;
    const int l15  = lane & 15;
    const int quad = lane >> 4;

    // XCD swizzle: batch pinned to an XCD pair so v (4MB) stays L2-resident
    const int lin  = blockIdx.x;                    // 0..255
    const int b    = (lin & 7) >> 1;
    const int iblk = ((lin >> 3) << 1) | (lin & 1);
    const int i0   = iblk * 64;

    const int iq  = w & 3;
    const int jq  = w >> 2;
    const int c0w = w * 32;                         // PV channel slice

    const size_t kbase = (size_t)b * N_ * M_;

    // q B-fragments (n = i = iq*16+l15, k = kh*32+quad*8), block-invariant
    f16x8 bqf[2];
    #pragma unroll
    for (int kh = 0; kh < 2; ++kh)
        bqf[kh] = *(const f16x8*)(qt + ((size_t)(b * N_ + i0 + iq * 16 + l15)) * M_
                                  + kh * 32 + quad * 8);

    // ---------------- pass 1: rowmax (registers only) ----------------
    float mx = -3.0e38f;   // per-lane: i = iq*16+l15, partial over (jq, quad)
    #pragma unroll 2
    for (int j0 = 0; j0 < N_; j0 += 64) {
        f32x4 s = {};
        #pragma unroll
        for (int kh = 0; kh < 2; ++kh) {
            f16x8 ak = *(const f16x8*)(kt + kbase + ((size_t)(j0 + jq * 16 + l15)) * M_
                                       + kh * 32 + quad * 8);
            s = __builtin_amdgcn_mfma_f32_16x16x32_f16(ak, bqf[kh], s, 0, 0, 0);
        }
        mx = fmaxf(mx, fmaxf(fmaxf(s[0], s[1]), fmaxf(s[2], s[3])));
    }
    mx = fmaxf(mx, __shfl_xor(mx, 16, 64));         // reduce over quads
    mx = fmaxf(mx, __shfl_xor(mx, 32, 64));
    if (lane < 16) sRm[jq][iq * 16 + l15] = mx;
    barrier_lgkm();
    const float mrow = fmaxf(fmaxf(sRm[0][iq * 16 + l15], sRm[1][iq * 16 + l15]),
                             fmaxf(sRm[2][iq * 16 + l15], sRm[3][iq * 16 + l15]));

    // ---------------- pass 2: P + PV ----------------
    f32x4 acc[2][4] = {};          // [ct][it]: rows c-local, cols i-local
    float l_acc = 0.f;

    #pragma unroll 2
    for (int j0 = 0; j0 < N_; j0 += 64) {
        const int buf = (j0 >> 6) & 1;

        // k loads FIRST (scores wait vmcnt(4), leaving v in flight)
        f16x8 ak[2];
        #pragma unroll
        for (int kh = 0; kh < 2; ++kh)
            ak[kh] = *(const f16x8*)(kt + kbase + ((size_t)(j0 + jq * 16 + l15)) * M_
                                     + kh * 32 + quad * 8);
        // v loads for THIS tile, consumed only after the barrier
        f16x8 vb[2][2];
        #pragma unroll
        for (int ct = 0; ct < 2; ++ct)
            #pragma unroll
            for (int kh = 0; kh < 2; ++kh)
                vb[ct][kh] = *(const f16x8*)(vh + ((size_t)(b * C_ + c0w + ct * 16 + l15)) * N_
                                             + j0 + kh * 32 + quad * 8);

        // scores: C col = i (l15), rows = j = jq*16 + quad*4 + r
        f32x4 s = {};
        #pragma unroll
        for (int kh = 0; kh < 2; ++kh)
            s = __builtin_amdgcn_mfma_f32_16x16x32_f16(ak[kh], bqf[kh], s, 0, 0, 0);

        f16x4 p4;
        #pragma unroll
        for (int r = 0; r < 4; ++r) {
            float p = __expf(s[r] - mrow);
            l_acc += p;
            p4[r] = (f16)p;
        }
        *(f16x4*)&sP[buf][iq * 16 + l15][jq * 16 + quad * 4] = p4;  // 8B write
        barrier_lgkm();

        // PV: pb = B-frag (n = i = it*16+l15, k = j)
        f16x8 pb[4][2];
        #pragma unroll
        for (int it = 0; it < 4; ++it)
            #pragma unroll
            for (int kh = 0; kh < 2; ++kh)
                pb[it][kh] = *(const f16x8*)&sP[buf][it * 16 + l15][kh * 32 + quad * 8];
        #pragma unroll
        for (int ct = 0; ct < 2; ++ct)
            #pragma unroll
            for (int it = 0; it < 4; ++it)
                #pragma unroll
                for (int kh = 0; kh < 2; ++kh)
                    acc[ct][it] = __builtin_amdgcn_mfma_f32_16x16x32_f16(
                        vb[ct][kh], pb[it][kh], acc[ct][it], 0, 0, 0);
    }

    // ---------------- l reduction ----------------
    l_acc += __shfl_xor(l_acc, 16, 64);
    l_acc += __shfl_xor(l_acc, 32, 64);
    if (lane < 16) sRl[jq][iq * 16 + l15] = l_acc;
    barrier_lgkm();

    // ---------------- epilogue: out = gamma * feat / l + x ----------------
    const float g = gamma[0];
    #pragma unroll
    for (int it = 0; it < 4; ++it) {
        const int il = it * 16 + l15;
        const float linv = 1.0f / (sRl[0][il] + sRl[1][il] + sRl[2][il] + sRl[3][il]);
        const int i = i0 + il;
        #pragma unroll
        for (int ct = 0; ct < 2; ++ct) {
            #pragma unroll
            for (int r = 0; r < 4; ++r) {
                const int c = c0w + ct * 16 + quad * 4 + r;
                const size_t idx = ((size_t)(b * C_ + c)) * N_ + i;
                out[idx] = g * (acc[ct][it][r] * linv) + x[idx];
            }
        }
    }
}

// ---------------------------------------------------------------------------
extern "C" void kernel_launch(void* const* d_in, const int* in_sizes, int n_in,
                              void* d_out, int out_size, void* d_ws, size_t ws_size,
                              hipStream_t stream)
{
    const float* x     = (const float*)d_in[0];
    const float* Wq    = (const float*)d_in[1];
    const float* bq    = (const float*)d_in[2];
    const float* Wk    = (const float*)d_in[3];
    const float* bk    = (const float*)d_in[4];
    const float* Wv    = (const float*)d_in[5];
    const float* bv    = (const float*)d_in[6];
    const float* gamma = (const float*)d_in[7];
    float* out = (float*)d_out;

    char* ws = (char*)d_ws;
    f16* xt = (f16*)ws;                                   // B*N*C   (16 MB)
    f16* qt = (f16*)(ws + (size_t)B_ * N_ * C_ * 2);      // B*N*M   ( 2 MB)
    f16* kt = qt + (size_t)B_ * N_ * M_;                  // B*N*M   ( 2 MB)
    f16* vh = kt + (size_t)B_ * N_ * M_;                  // B*C*N   (16 MB)

    transpose_cast<<<dim3(N_ / 64, C_ / 64, B_), 256, 0, stream>>>(x, xt);
    qkv_gemm<<<dim3(N_ / 128, 10, B_), 512, 0, stream>>>(
        xt, Wq, bq, Wk, bk, Wv, bv, qt, kt, vh);
    attn<<<dim3(256), 1024, 0, stream>>>(qt, kt, vh, x, gamma, out);
}